// Round 6
// baseline (175.925 us; speedup 1.0000x reference)
//
#include <hip/hip_runtime.h>

// Shapes
#define NB   256      // batch
#define E0   300      // embedding
#define EP   304      // padded embedding
#define F_   512      // features
#define KP   1536     // padded K (5*304=1520 -> 48*32)
#define NKT  48       // K-steps of 32
#define LQ_  64
#define LA_  256

typedef __attribute__((ext_vector_type(4))) float f32x4;
typedef __attribute__((ext_vector_type(8))) short short8;

#define XQ_ELEMS (NB * (LQ_ + 4) * EP)   // 5,292,032
#define XA_ELEMS (NB * (LA_ + 4) * EP)   // 20,234,240
#define WF_ELEMS (F_ * KP)               // 786,432 (fragment-packed)
#define OUTQ_ELEMS ((size_t)NB * F_ * LQ_)
#define XROWS (NB * (LQ_ + 4) + NB * (LA_ + 4))   // 83,968

__device__ __forceinline__ unsigned short f2bf(float x) {
    unsigned int u = __float_as_uint(x);
    u = u + 0x7fffu + ((u >> 16) & 1u);   // RNE
    return (unsigned short)(u >> 16);
}

// Zero-padded bf16 x with halo, flat-indexed dense blocks.
// slot = row*76 + col; col<75 -> float4 of source row; col=75 -> tail pad.
__global__ void prep_x(const float* __restrict__ q, const float* __restrict__ a,
                       unsigned short* __restrict__ xq, unsigned short* __restrict__ xa)
{
    int idx = blockIdx.x * 256 + threadIdx.x;
    if (idx >= XROWS * 76) return;
    int row = idx / 76;
    int col = idx - row * 76;

    const float* src;
    unsigned short* dst;
    bool valid;
    if (row < NB * (LQ_ + 4)) {
        int b = row / (LQ_ + 4), lp = row - b * (LQ_ + 4);
        dst = xq + (size_t)row * EP;
        valid = (lp >= 2 && lp < 2 + LQ_);
        src = q + ((size_t)b * LQ_ + (lp - 2)) * E0;
    } else {
        int r2 = row - NB * (LQ_ + 4);
        int b = r2 / (LA_ + 4), lp = r2 - b * (LA_ + 4);
        dst = xa + (size_t)r2 * EP;
        valid = (lp >= 2 && lp < 2 + LA_);
        src = a + ((size_t)b * LA_ + (lp - 2)) * E0;
    }
    unsigned long long pk = 0ull;
    if (valid && col < 75) {   // rows are 1200B stride -> float4-aligned
        const float4 v = reinterpret_cast<const float4*>(src)[col];
        pk = (unsigned long long)f2bf(v.x)
           | ((unsigned long long)f2bf(v.y) << 16)
           | ((unsigned long long)f2bf(v.z) << 32)
           | ((unsigned long long)f2bf(v.w) << 48);
    }
    *reinterpret_cast<unsigned long long*>(dst + (size_t)col * 4) = pk;
}

// Fragment-packed W: chunk (tile16, kc) is 1024B holding the exact per-lane
// A-operand of mfma_16x16x32: lane holds f = tile16*16 + (lane&15),
// k' = kc*32 + (lane>>4)*8 + j.  (Verified r1-r4.)
__global__ void prep_w2(const float* __restrict__ W, unsigned short* __restrict__ wfr)
{
    int idx = blockIdx.x * 256 + threadIdx.x;     // grid = 32*48*512 shorts
    int j    = idx & 7;
    int lane = (idx >> 3) & 63;
    int chunk = idx >> 9;
    int kc = chunk % NKT;
    int tile16 = chunk / NKT;
    int f  = tile16 * 16 + (lane & 15);
    int kp = kc * 32 + (lane >> 4) * 8 + j;
    int jj = kp / EP;
    int e  = kp - jj * EP;
    float v = (kp < 5 * EP && e < E0) ? W[(size_t)(jj * E0 + e) * F_ + f] : 0.f;
    wfr[idx] = f2bf(v);
}

// 256f x 64l tile, 4 waves (wave = 64f x 64l, acc[4][4] = 64 AGPR), BK=32.
// Z: ring-4 LDS (16 KB) via global_load_lds, staged 3 ahead.
// W: L2->reg ping-pong (32 VGPR), in flight one full K-step.
// One s_barrier + one counted vmcnt fence + one lgkm drain per K-step.
// launch_bounds(256,3): cap 170 regs (est ~137) -> 3 blocks/CU = 3 waves/SIMD.
__global__ __launch_bounds__(256, 3) void qa_gemm(
    const unsigned short* __restrict__ xq,
    const unsigned short* __restrict__ xa,
    const unsigned short* __restrict__ wfr,
    const float* __restrict__ bias,
    float* __restrict__ out)
{
    __shared__ __align__(16) unsigned short lds[4 * 2048];   // 16 KB Z-ring

    const int bid = blockIdx.x;
    const int wg  = (bid & 7) * 320 + (bid >> 3);   // XCD swizzle, 2560 % 8 == 0

    const unsigned short* xp;
    float* ob;
    int Mbase, lsh, Lp, ftBase;
    if (wg < 512) {                 // question: 256 l-tiles x 2 f-halves
        Mbase  = (wg >> 1) * 64;
        ftBase = (wg & 1) * 256;
        xp = xq; lsh = 6; Lp = LQ_ + 4;
        ob = out;
    } else {                        // answer: 1024 l-tiles x 2 f-halves
        const int id = wg - 512;
        Mbase  = (id >> 1) * 64;
        ftBase = (id & 1) * 256;
        xp = xa; lsh = 8; Lp = LA_ + 4;
        ob = out + OUTQ_ELEMS;
    }
    const int Lv = 1 << lsh;

    const int tid  = threadIdx.x;
    const int lane = tid & 63;
    const int wid  = tid >> 6;      // wave = f-slice (0..3); all share the l-tile
    const int lq   = lane >> 4;
    const int lr   = lane & 15;

    // ---- Z staging geometry (swizzle verified r1-r4): wave stages 16 rows (1 instr)
    const int s_c  = (lane & 3) ^ ((lane >> 3) & 3);
    const int sub  = lane >> 2;
    const int mr0 = Mbase + wid * 16 + sub;
    const unsigned short* gZ0 = xp + (size_t)((mr0 >> lsh) * Lp + (mr0 & (Lv - 1))) * EP + s_c * 8;
    const int dz0 = wid * 512;      // shorts

#define GLLDS(p, d) __builtin_amdgcn_global_load_lds(                               \
        (const __attribute__((address_space(1))) void*)(p),                         \
        (__attribute__((address_space(3))) void*)(d), 16, 0, 0)
#define STAGE_Z(T) do { const int rb = ((T) & 3) * 2048; const size_t ko = (size_t)(T) * 32; \
    GLLDS(gZ0 + ko, lds + dz0 + rb); } while (0)

    // ---- W fragment pointers (frag = 512 shorts; step t -> +512 shorts)
    const unsigned short* wpc0 = wfr + (size_t)((ftBase >> 4) + wid * 4 + 0) * NKT * 512 + lane * 8;
    const unsigned short* wpc1 = wfr + (size_t)((ftBase >> 4) + wid * 4 + 1) * NKT * 512 + lane * 8;
    const unsigned short* wpc2 = wfr + (size_t)((ftBase >> 4) + wid * 4 + 2) * NKT * 512 + lane * 8;
    const unsigned short* wpc3 = wfr + (size_t)((ftBase >> 4) + wid * 4 + 3) * NKT * 512 + lane * 8;

#define WLOAD(dst, p) do {                                                           \
    asm volatile("global_load_dwordx4 %0, %1, off" : "=v"(dst) : "v"(p) : "memory"); \
    (p) += 512; } while (0)

    // ---- Z fragment LDS offsets (bytes), chunk-swizzled (verified r1-r4)
    const int cs = (lq ^ ((lr >> 1) & 3)) * 16;
    int zoff[4];
#pragma unroll
    for (int n = 0; n < 4; ++n) zoff[n] = (n * 16 + lr) * 64 + cs;

    f32x4 acc[4][4] = {};
    short8 WA0, WA1, WA2, WA3, WB0, WB1, WB2, WB3;

#define MFMA(a, b, c) __builtin_amdgcn_mfma_f32_16x16x32_bf16((a), (b), (c), 0, 0, 0)

    // Per-wave VMEM order: step t issues [W(t+1) x4, Z(t+3)].
    // Steady unretired at phase-A fence of t: [Z(t+1), W(t)x4, Z(t+2), W(t+1)x4, Z(t+3)]
    //   -> vmcnt(6) retires W(t) (and Z(t+1)), keeps prefetches in flight.
    // Z(t) publication: own-retire at fence(t-1) + end-barrier(t-1).
    // Buffer safety (ring-4): Z(t+3)->buf[(t-1)&3]; all reads of buf[t-1] are
    // lgkm-drained before end-barrier(t-1), and the stage is issued after it.
#define KSTEP(T, C0, C1, C2, C3, N0, N1, N2, N3, DO_W, DO_Z, AV) do {               \
    const char* bb = (const char*)lds + ((T) & 3) * 4096;                           \
    short8 z01[2], z23[2];                                                          \
    _Pragma("unroll") for (int n = 0; n < 2; ++n) z01[n] = *(const short8*)(bb + zoff[n]); \
    if (DO_W) { WLOAD(N0, wpc0); WLOAD(N1, wpc1); WLOAD(N2, wpc2); WLOAD(N3, wpc3); } \
    if (DO_Z) { STAGE_Z((T) + 3); }                                                 \
    asm volatile("s_waitcnt vmcnt(" #AV ") lgkmcnt(0)" ::: "memory");               \
    __builtin_amdgcn_sched_barrier(0);                                              \
    __builtin_amdgcn_s_setprio(1);                                                  \
    _Pragma("unroll") for (int n = 0; n < 2; ++n) {                                 \
        acc[0][n] = MFMA(C0, z01[n], acc[0][n]);                                    \
        acc[1][n] = MFMA(C1, z01[n], acc[1][n]);                                    \
        acc[2][n] = MFMA(C2, z01[n], acc[2][n]);                                    \
        acc[3][n] = MFMA(C3, z01[n], acc[3][n]);                                    \
    }                                                                               \
    __builtin_amdgcn_s_setprio(0);                                                  \
    __builtin_amdgcn_sched_barrier(0);                                              \
    _Pragma("unroll") for (int n = 0; n < 2; ++n) z23[n] = *(const short8*)(bb + zoff[2 + n]); \
    asm volatile("s_waitcnt lgkmcnt(0)\n\ts_barrier" ::: "memory");                 \
    __builtin_amdgcn_sched_barrier(0);                                              \
    __builtin_amdgcn_s_setprio(1);                                                  \
    _Pragma("unroll") for (int n = 0; n < 2; ++n) {                                 \
        acc[0][2 + n] = MFMA(C0, z23[n], acc[0][2 + n]);                            \
        acc[1][2 + n] = MFMA(C1, z23[n], acc[1][2 + n]);                            \
        acc[2][2 + n] = MFMA(C2, z23[n], acc[2][2 + n]);                            \
        acc[3][2 + n] = MFMA(C3, z23[n], acc[3][2 + n]);                            \
    }                                                                               \
    __builtin_amdgcn_s_setprio(0);                                                  \
    __builtin_amdgcn_sched_barrier(0);                                              \
} while (0)

    // Prologue: W(0) x4, Z(0..2); vmcnt(2) retires W0+Z0, keeps [Z1, Z2]; publish.
    WLOAD(WA0, wpc0); WLOAD(WA1, wpc1); WLOAD(WA2, wpc2); WLOAD(WA3, wpc3);
    STAGE_Z(0); STAGE_Z(1); STAGE_Z(2);
    asm volatile("s_waitcnt vmcnt(2)\n\ts_barrier" ::: "memory");

    for (int i = 0; i < 22; ++i) {          // t = 0..43
        const int t = 2 * i;
        KSTEP(t,     WA0, WA1, WA2, WA3, WB0, WB1, WB2, WB3, 1, 1, 6);
        KSTEP(t + 1, WB0, WB1, WB2, WB3, WA0, WA1, WA2, WA3, 1, 1, 6);
    }
    KSTEP(44, WA0, WA1, WA2, WA3, WB0, WB1, WB2, WB3, 1, 1, 6);   // +W45, +Z47
    KSTEP(45, WB0, WB1, WB2, WB3, WA0, WA1, WA2, WA3, 1, 0, 5);   // +W46
    KSTEP(46, WA0, WA1, WA2, WA3, WB0, WB1, WB2, WB3, 1, 0, 4);   // +W47
    KSTEP(47, WB0, WB1, WB2, WB3, WA0, WA1, WA2, WA3, 0, 0, 0);

#undef KSTEP
#undef WLOAD
#undef STAGE_Z
#undef GLLDS
#undef MFMA

    // ---- epilogue: D row = f = lq*4+reg, col = l = lr (verified r1-r4)
#pragma unroll
    for (int ns = 0; ns < 4; ++ns) {
        const int m = Mbase + ns * 16 + lr;
        const int b = m >> lsh;
        const int l = m & (Lv - 1);
        float* orow = ob + ((size_t)b * F_ << lsh) + l;
#pragma unroll
        for (int ms = 0; ms < 4; ++ms) {
            const int f0 = ftBase + wid * 64 + ms * 16 + lq * 4;
            const f32x4 v = acc[ms][ns];
#pragma unroll
            for (int r = 0; r < 4; ++r)
                orow[(size_t)(f0 + r) << lsh] = v[r] + __ldg(&bias[f0 + r]);
        }
    }
}

extern "C" void kernel_launch(void* const* d_in, const int* in_sizes, int n_in,
                              void* d_out, int out_size, void* d_ws, size_t ws_size,
                              hipStream_t stream)
{
    const float* q    = (const float*)d_in[0];
    const float* a    = (const float*)d_in[1];
    const float* W    = (const float*)d_in[2];
    const float* bias = (const float*)d_in[3];
    float* out = (float*)d_out;

    unsigned short* xq  = (unsigned short*)d_ws;
    unsigned short* xa  = xq + XQ_ELEMS;
    unsigned short* wfr = xa + XA_ELEMS;
    // ws needed: (XQ+XA+WF)*2 = 52.6 MB

    prep_x<<<(XROWS * 76 + 255) / 256, 256, 0, stream>>>(q, a, xq, xa);
    prep_w2<<<WF_ELEMS / 256, 256, 0, stream>>>(W, wfr);
    qa_gemm<<<2560, 256, 0, stream>>>(xq, xa, wfr, bias, out);
}

// Round 7
// 169.024 us; speedup vs baseline: 1.0408x; 1.0408x over previous
//
#include <hip/hip_runtime.h>

// Shapes
#define NB   256      // batch
#define E0   300      // embedding
#define EP   304      // padded embedding
#define F_   512      // features
#define KP   1536     // padded K (5*304=1520 -> 48*32)
#define NKT  48       // K-steps of 32
#define LQ_  64
#define LA_  256

typedef __attribute__((ext_vector_type(4))) float f32x4;
typedef __attribute__((ext_vector_type(8))) short short8;

#define XQ_ELEMS (NB * (LQ_ + 4) * EP)   // 5,292,032
#define XA_ELEMS (NB * (LA_ + 4) * EP)   // 20,234,240
#define WF_ELEMS (F_ * KP)               // 786,432 (fragment-packed)
#define OUTQ_ELEMS ((size_t)NB * F_ * LQ_)
#define XROWS (NB * (LQ_ + 4) + NB * (LA_ + 4))   // 83,968

__device__ __forceinline__ unsigned short f2bf(float x) {
    unsigned int u = __float_as_uint(x);
    u = u + 0x7fffu + ((u >> 16) & 1u);   // RNE
    return (unsigned short)(u >> 16);
}

// Zero-padded bf16 x with halo, flat-indexed dense blocks.
__global__ void prep_x(const float* __restrict__ q, const float* __restrict__ a,
                       unsigned short* __restrict__ xq, unsigned short* __restrict__ xa)
{
    int idx = blockIdx.x * 256 + threadIdx.x;
    if (idx >= XROWS * 76) return;
    int row = idx / 76;
    int col = idx - row * 76;

    const float* src;
    unsigned short* dst;
    bool valid;
    if (row < NB * (LQ_ + 4)) {
        int b = row / (LQ_ + 4), lp = row - b * (LQ_ + 4);
        dst = xq + (size_t)row * EP;
        valid = (lp >= 2 && lp < 2 + LQ_);
        src = q + ((size_t)b * LQ_ + (lp - 2)) * E0;
    } else {
        int r2 = row - NB * (LQ_ + 4);
        int b = r2 / (LA_ + 4), lp = r2 - b * (LA_ + 4);
        dst = xa + (size_t)r2 * EP;
        valid = (lp >= 2 && lp < 2 + LA_);
        src = a + ((size_t)b * LA_ + (lp - 2)) * E0;
    }
    unsigned long long pk = 0ull;
    if (valid && col < 75) {   // rows are 1200B stride -> float4-aligned
        const float4 v = reinterpret_cast<const float4*>(src)[col];
        pk = (unsigned long long)f2bf(v.x)
           | ((unsigned long long)f2bf(v.y) << 16)
           | ((unsigned long long)f2bf(v.z) << 32)
           | ((unsigned long long)f2bf(v.w) << 48);
    }
    *reinterpret_cast<unsigned long long*>(dst + (size_t)col * 4) = pk;
}

// Fragment-packed W: chunk (tile16, kc) is 1024B holding the exact per-lane
// A-operand of mfma_16x16x32: lane holds f = tile16*16 + (lane&15),
// k' = kc*32 + (lane>>4)*8 + j.  (Verified r1-r6.)
__global__ void prep_w2(const float* __restrict__ W, unsigned short* __restrict__ wfr)
{
    int idx = blockIdx.x * 256 + threadIdx.x;     // grid = 32*48*512 shorts
    int j    = idx & 7;
    int lane = (idx >> 3) & 63;
    int chunk = idx >> 9;
    int kc = chunk % NKT;
    int tile16 = chunk / NKT;
    int f  = tile16 * 16 + (lane & 15);
    int kp = kc * 32 + (lane >> 4) * 8 + j;
    int jj = kp / EP;
    int e  = kp - jj * EP;
    float v = (kp < 5 * EP && e < E0) ? W[(size_t)(jj * E0 + e) * F_ + f] : 0.f;
    wfr[idx] = f2bf(v);
}

// 256f x 64l tile, 4 waves (wave = 64f x 64l, acc[4][4]), BK=32.
// Z: ring-4 LDS (16 KB) via global_load_lds, staged 3 ahead.
// W: L2->reg ping-pong, in flight one full K-step.
// r7 ablation: NO setprio, NO MFMA-cluster sched pinning, ONE barrier + ONE
// combined counted fence per K-step.  vmcnt ledger identical to r6 (passed):
// per-step VMEM order [W x4, Z x1]; at fence of step t outstanding =
// [Z(t+1), W(t)x4, Z(t+2), W(t+1)x4, Z(t+3)] = 11 -> vmcnt(6) retires
// Z(t+1)+W(t).  Publication of Z(t): own fence at t-1 + end-barrier of t-1.
// Ring safety: stage of Z(t+3) -> buf[(t-1)&3], issued after the barrier that
// followed all (fence-drained) reads of that buf in step t-1.
__global__ __launch_bounds__(256, 3) void qa_gemm(
    const unsigned short* __restrict__ xq,
    const unsigned short* __restrict__ xa,
    const unsigned short* __restrict__ wfr,
    const float* __restrict__ bias,
    float* __restrict__ out)
{
    __shared__ __align__(16) unsigned short lds[4 * 2048];   // 16 KB Z-ring

    const int bid = blockIdx.x;
    const int wg  = (bid & 7) * 320 + (bid >> 3);   // XCD swizzle, 2560 % 8 == 0

    const unsigned short* xp;
    float* ob;
    int Mbase, lsh, Lp, ftBase;
    if (wg < 512) {                 // question: 256 l-tiles x 2 f-halves
        Mbase  = (wg >> 1) * 64;
        ftBase = (wg & 1) * 256;
        xp = xq; lsh = 6; Lp = LQ_ + 4;
        ob = out;
    } else {                        // answer: 1024 l-tiles x 2 f-halves
        const int id = wg - 512;
        Mbase  = (id >> 1) * 64;
        ftBase = (id & 1) * 256;
        xp = xa; lsh = 8; Lp = LA_ + 4;
        ob = out + OUTQ_ELEMS;
    }
    const int Lv = 1 << lsh;

    const int tid  = threadIdx.x;
    const int lane = tid & 63;
    const int wid  = tid >> 6;      // wave = f-slice (0..3); all share the l-tile
    const int lq   = lane >> 4;
    const int lr   = lane & 15;

    // ---- Z staging geometry (swizzle verified r1-r6): wave stages 16 rows
    const int s_c  = (lane & 3) ^ ((lane >> 3) & 3);
    const int sub  = lane >> 2;
    const int mr0 = Mbase + wid * 16 + sub;
    const unsigned short* gZ0 = xp + (size_t)((mr0 >> lsh) * Lp + (mr0 & (Lv - 1))) * EP + s_c * 8;
    const int dz0 = wid * 512;      // shorts

#define GLLDS(p, d) __builtin_amdgcn_global_load_lds(                               \
        (const __attribute__((address_space(1))) void*)(p),                         \
        (__attribute__((address_space(3))) void*)(d), 16, 0, 0)
#define STAGE_Z(T) do { const int rb = ((T) & 3) * 2048; const size_t ko = (size_t)(T) * 32; \
    GLLDS(gZ0 + ko, lds + dz0 + rb); } while (0)

    // ---- W fragment pointers (frag = 512 shorts; step t -> +512 shorts)
    const unsigned short* wpc0 = wfr + (size_t)((ftBase >> 4) + wid * 4 + 0) * NKT * 512 + lane * 8;
    const unsigned short* wpc1 = wfr + (size_t)((ftBase >> 4) + wid * 4 + 1) * NKT * 512 + lane * 8;
    const unsigned short* wpc2 = wfr + (size_t)((ftBase >> 4) + wid * 4 + 2) * NKT * 512 + lane * 8;
    const unsigned short* wpc3 = wfr + (size_t)((ftBase >> 4) + wid * 4 + 3) * NKT * 512 + lane * 8;

#define WLOAD(dst, p) do {                                                           \
    asm volatile("global_load_dwordx4 %0, %1, off" : "=v"(dst) : "v"(p) : "memory"); \
    (p) += 512; } while (0)

    // ---- Z fragment LDS offsets (bytes), chunk-swizzled (verified r1-r6)
    const int cs = (lq ^ ((lr >> 1) & 3)) * 16;
    int zoff[4];
#pragma unroll
    for (int n = 0; n < 4; ++n) zoff[n] = (n * 16 + lr) * 64 + cs;

    f32x4 acc[4][4] = {};
    short8 WA0, WA1, WA2, WA3, WB0, WB1, WB2, WB3;

#define MFMA(a, b, c) __builtin_amdgcn_mfma_f32_16x16x32_bf16((a), (b), (c), 0, 0, 0)

    // One K-step, de-pinned: reads -> loads -> stage -> combined counted fence
    // -> (sched_barrier for rule #18) -> 16 MFMA -> end barrier.
#define KSTEP(T, C0, C1, C2, C3, N0, N1, N2, N3, DO_W, DO_Z, AV) do {               \
    const char* bb = (const char*)lds + ((T) & 3) * 4096;                           \
    short8 zf[4];                                                                   \
    _Pragma("unroll") for (int n = 0; n < 4; ++n) zf[n] = *(const short8*)(bb + zoff[n]); \
    if (DO_W) { WLOAD(N0, wpc0); WLOAD(N1, wpc1); WLOAD(N2, wpc2); WLOAD(N3, wpc3); } \
    if (DO_Z) { STAGE_Z((T) + 3); }                                                 \
    asm volatile("s_waitcnt vmcnt(" #AV ") lgkmcnt(0)" ::: "memory");               \
    __builtin_amdgcn_sched_barrier(0);                                              \
    _Pragma("unroll") for (int n = 0; n < 4; ++n) {                                 \
        acc[0][n] = MFMA(C0, zf[n], acc[0][n]);                                     \
        acc[1][n] = MFMA(C1, zf[n], acc[1][n]);                                     \
        acc[2][n] = MFMA(C2, zf[n], acc[2][n]);                                     \
        acc[3][n] = MFMA(C3, zf[n], acc[3][n]);                                     \
    }                                                                               \
    asm volatile("s_barrier" ::: "memory");                                         \
} while (0)

    // Prologue: W(0) x4, Z(0..2); vmcnt(2) retires W0+Z0, keeps [Z1, Z2]; publish.
    WLOAD(WA0, wpc0); WLOAD(WA1, wpc1); WLOAD(WA2, wpc2); WLOAD(WA3, wpc3);
    STAGE_Z(0); STAGE_Z(1); STAGE_Z(2);
    asm volatile("s_waitcnt vmcnt(2)\n\ts_barrier" ::: "memory");

    for (int i = 0; i < 22; ++i) {          // t = 0..43
        const int t = 2 * i;
        KSTEP(t,     WA0, WA1, WA2, WA3, WB0, WB1, WB2, WB3, 1, 1, 6);
        KSTEP(t + 1, WB0, WB1, WB2, WB3, WA0, WA1, WA2, WA3, 1, 1, 6);
    }
    KSTEP(44, WA0, WA1, WA2, WA3, WB0, WB1, WB2, WB3, 1, 1, 6);   // +W45, +Z47
    KSTEP(45, WB0, WB1, WB2, WB3, WA0, WA1, WA2, WA3, 1, 0, 5);   // +W46
    KSTEP(46, WA0, WA1, WA2, WA3, WB0, WB1, WB2, WB3, 1, 0, 4);   // +W47
    KSTEP(47, WB0, WB1, WB2, WB3, WA0, WA1, WA2, WA3, 0, 0, 0);

#undef KSTEP
#undef WLOAD
#undef STAGE_Z
#undef GLLDS
#undef MFMA

    // ---- epilogue: D row = f = lq*4+reg, col = l = lr (verified r1-r6)
#pragma unroll
    for (int ns = 0; ns < 4; ++ns) {
        const int m = Mbase + ns * 16 + lr;
        const int b = m >> lsh;
        const int l = m & (Lv - 1);
        float* orow = ob + ((size_t)b * F_ << lsh) + l;
#pragma unroll
        for (int ms = 0; ms < 4; ++ms) {
            const int f0 = ftBase + wid * 64 + ms * 16 + lq * 4;
            const f32x4 v = acc[ms][ns];
#pragma unroll
            for (int r = 0; r < 4; ++r)
                orow[(size_t)(f0 + r) << lsh] = v[r] + __ldg(&bias[f0 + r]);
        }
    }
}

extern "C" void kernel_launch(void* const* d_in, const int* in_sizes, int n_in,
                              void* d_out, int out_size, void* d_ws, size_t ws_size,
                              hipStream_t stream)
{
    const float* q    = (const float*)d_in[0];
    const float* a    = (const float*)d_in[1];
    const float* W    = (const float*)d_in[2];
    const float* bias = (const float*)d_in[3];
    float* out = (float*)d_out;

    unsigned short* xq  = (unsigned short*)d_ws;
    unsigned short* xa  = xq + XQ_ELEMS;
    unsigned short* wfr = xa + XA_ELEMS;
    // ws needed: (XQ+XA+WF)*2 = 52.6 MB

    prep_x<<<(XROWS * 76 + 255) / 256, 256, 0, stream>>>(q, a, xq, xa);
    prep_w2<<<WF_ELEMS / 256, 256, 0, stream>>>(W, wfr);
    qa_gemm<<<2560, 256, 0, stream>>>(xq, xa, wfr, bias, out);
}

// Round 8
// 164.097 us; speedup vs baseline: 1.0721x; 1.0300x over previous
//
#include <hip/hip_runtime.h>

// Shapes
#define NB   256      // batch
#define E0   300      // embedding
#define EP   304      // padded embedding
#define F_   512      // features
#define KP   1536     // padded K (5*304=1520 -> 48*32)
#define NKT  48       // K-steps of 32
#define NSS  12       // super-steps of BK=128
#define LQ_  64
#define LA_  256

typedef __attribute__((ext_vector_type(4))) float f32x4;
typedef __attribute__((ext_vector_type(8))) short short8;

#define XQ_ELEMS (NB * (LQ_ + 4) * EP)   // 5,292,032
#define XA_ELEMS (NB * (LA_ + 4) * EP)   // 20,234,240
#define WF_ELEMS (F_ * KP)               // 786,432 (fragment-packed)
#define OUTQ_ELEMS ((size_t)NB * F_ * LQ_)
#define XROWS (NB * (LQ_ + 4) + NB * (LA_ + 4))   // 83,968

__device__ __forceinline__ unsigned short f2bf(float x) {
    unsigned int u = __float_as_uint(x);
    u = u + 0x7fffu + ((u >> 16) & 1u);   // RNE
    return (unsigned short)(u >> 16);
}

// Zero-padded bf16 x with halo, flat-indexed dense blocks.
__global__ void prep_x(const float* __restrict__ q, const float* __restrict__ a,
                       unsigned short* __restrict__ xq, unsigned short* __restrict__ xa)
{
    int idx = blockIdx.x * 256 + threadIdx.x;
    if (idx >= XROWS * 76) return;
    int row = idx / 76;
    int col = idx - row * 76;

    const float* src;
    unsigned short* dst;
    bool valid;
    if (row < NB * (LQ_ + 4)) {
        int b = row / (LQ_ + 4), lp = row - b * (LQ_ + 4);
        dst = xq + (size_t)row * EP;
        valid = (lp >= 2 && lp < 2 + LQ_);
        src = q + ((size_t)b * LQ_ + (lp - 2)) * E0;
    } else {
        int r2 = row - NB * (LQ_ + 4);
        int b = r2 / (LA_ + 4), lp = r2 - b * (LA_ + 4);
        dst = xa + (size_t)r2 * EP;
        valid = (lp >= 2 && lp < 2 + LA_);
        src = a + ((size_t)b * LA_ + (lp - 2)) * E0;
    }
    unsigned long long pk = 0ull;
    if (valid && col < 75) {   // rows are 1200B stride -> float4-aligned
        const float4 v = reinterpret_cast<const float4*>(src)[col];
        pk = (unsigned long long)f2bf(v.x)
           | ((unsigned long long)f2bf(v.y) << 16)
           | ((unsigned long long)f2bf(v.z) << 32)
           | ((unsigned long long)f2bf(v.w) << 48);
    }
    *reinterpret_cast<unsigned long long*>(dst + (size_t)col * 4) = pk;
}

// Fragment-packed W: chunk (tile16, kc) is 1024B holding the exact per-lane
// A-operand of mfma_16x16x32: lane holds f = tile16*16 + (lane&15),
// k' = kc*32 + (lane>>4)*8 + j.  (Verified r1-r7.)
__global__ void prep_w2(const float* __restrict__ W, unsigned short* __restrict__ wfr)
{
    int idx = blockIdx.x * 256 + threadIdx.x;     // grid = 32*48*512 shorts
    int j    = idx & 7;
    int lane = (idx >> 3) & 63;
    int chunk = idx >> 9;
    int kc = chunk % NKT;
    int tile16 = chunk / NKT;
    int f  = tile16 * 16 + (lane & 15);
    int kp = kc * 32 + (lane >> 4) * 8 + j;
    int jj = kp / EP;
    int e  = kp - jj * EP;
    float v = (kp < 5 * EP && e < E0) ? W[(size_t)(jj * E0 + e) * F_ + f] : 0.f;
    wfr[idx] = f2bf(v);
}

// 256f x 64l tile, 4 waves (wave = 64f x 64l, acc[4][4]), BK=128 super-steps.
// Z: ring-2 LDS (2 x 16 KB, as 4 ksub blocks of [64][32]) via global_load_lds.
// W: L2->reg ping-pong at ksub granularity.  ONE s_barrier per super-step (12
// total); all other waits counted (vmcnt/lgkmcnt never conservatively 0 except
// tile-internal tails).  Ledger (per-wave, in-order):
//   prologue: [W(0,0)x4, stage(0)x4] -> vmcnt(0), barrier.
//   super-step S (0..10): start: stage(S+1)x4, read zA(ks0).
//     ks0: read zB(ks1), W(S,1)x4 -> vmcnt(8)  [retires W(S,0)] lgkm(4)
//     ks1: read zA(ks2), W(S,2)x4 -> vmcnt(4)  [retires stage(S+1)+W(S,1)] lgkm(4)
//     ks2: read zB(ks3), W(S,3)x4 -> vmcnt(4)  [retires W(S,2)] lgkm(4)
//     ks3:              W(S+1,0)x4 -> vmcnt(4) [retires W(S,3)] lgkm(0); barrier.
//   Publication: every wave's stage(S+1) retired at its ks1 fence, before the
//   end-of-S barrier; reads of buf[S+1] only after that barrier.  Ring-2 reuse:
//   stage(S+1) hits the buffer read in S-1, whose reads completed before S-1's
//   end barrier, after which the stage is issued.
//   S=11 (no stage): fences vmcnt(4/4/4/0), lgkm(4/4/4/0), no end barrier.
__global__ __launch_bounds__(256, 3) void qa_gemm(
    const unsigned short* __restrict__ xq,
    const unsigned short* __restrict__ xa,
    const unsigned short* __restrict__ wfr,
    const float* __restrict__ bias,
    float* __restrict__ out)
{
    __shared__ __align__(16) unsigned short lds[2 * 8192];   // 32 KB Z-ring

    const int bid = blockIdx.x;
    const int wg  = (bid & 7) * 320 + (bid >> 3);   // XCD swizzle, 2560 % 8 == 0

    const unsigned short* xp;
    float* ob;
    int Mbase, lsh, Lp, ftBase;
    if (wg < 512) {                 // question: 256 l-tiles x 2 f-halves
        Mbase  = (wg >> 1) * 64;
        ftBase = (wg & 1) * 256;
        xp = xq; lsh = 6; Lp = LQ_ + 4;
        ob = out;
    } else {                        // answer: 1024 l-tiles x 2 f-halves
        const int id = wg - 512;
        Mbase  = (id >> 1) * 64;
        ftBase = (id & 1) * 256;
        xp = xa; lsh = 8; Lp = LA_ + 4;
        ob = out + OUTQ_ELEMS;
    }
    const int Lv = 1 << lsh;

    const int tid  = threadIdx.x;
    const int lane = tid & 63;
    const int wid  = tid >> 6;      // wave = f-slice (0..3); all share the l-tile
    const int lq   = lane >> 4;
    const int lr   = lane & 15;

    // ---- Z staging geometry (swizzle verified r1-r7): wave stages 16 rows/ksub
    const int s_c  = (lane & 3) ^ ((lane >> 3) & 3);
    const int sub  = lane >> 2;
    const int mr0 = Mbase + wid * 16 + sub;
    const unsigned short* gZ0 = xp + (size_t)((mr0 >> lsh) * Lp + (mr0 & (Lv - 1))) * EP + s_c * 8;
    const int dz0 = wid * 512;      // shorts, within each 4K-short ksub block

#define GLLDS(p, d) __builtin_amdgcn_global_load_lds(                               \
        (const __attribute__((address_space(1))) void*)(p),                         \
        (__attribute__((address_space(3))) void*)(d), 16, 0, 0)
// Stage super-tile T (cols T*128..T*128+127) as 4 ksub blocks of [64][32]
#define STAGE_SS(T) do { const int rb = ((T) & 1) * 8192; const size_t ko = (size_t)(T) * 128; \
    GLLDS(gZ0 + ko +  0, lds + rb + 0 * 2048 + dz0);                                \
    GLLDS(gZ0 + ko + 32, lds + rb + 1 * 2048 + dz0);                                \
    GLLDS(gZ0 + ko + 64, lds + rb + 2 * 2048 + dz0);                                \
    GLLDS(gZ0 + ko + 96, lds + rb + 3 * 2048 + dz0); } while (0)

    // ---- W fragment pointers (frag = 512 shorts; each WLOAD advances one kc)
    const unsigned short* wpc0 = wfr + (size_t)((ftBase >> 4) + wid * 4 + 0) * NKT * 512 + lane * 8;
    const unsigned short* wpc1 = wfr + (size_t)((ftBase >> 4) + wid * 4 + 1) * NKT * 512 + lane * 8;
    const unsigned short* wpc2 = wfr + (size_t)((ftBase >> 4) + wid * 4 + 2) * NKT * 512 + lane * 8;
    const unsigned short* wpc3 = wfr + (size_t)((ftBase >> 4) + wid * 4 + 3) * NKT * 512 + lane * 8;

#define WLOAD(dst, p) do {                                                           \
    asm volatile("global_load_dwordx4 %0, %1, off" : "=v"(dst) : "v"(p) : "memory"); \
    (p) += 512; } while (0)

    // ---- Z fragment LDS offsets within a ksub block (bytes), verified r1-r7
    const int cs = (lq ^ ((lr >> 1) & 3)) * 16;
    int zoff[4];
#pragma unroll
    for (int n = 0; n < 4; ++n) zoff[n] = (n * 16 + lr) * 64 + cs;

    f32x4 acc[4][4] = {};
    short8 zA[4], zB[4], wA[4], wB[4];

#define MFMA(a, b, c) __builtin_amdgcn_mfma_f32_16x16x32_bf16((a), (b), (c), 0, 0, 0)

    // One ksub: optionally read next-ksub Z frags, optionally load next W group,
    // counted fence, 16 MFMA.
#define KSUB(bb, NXT, ZU, ZL, WU, WL, DO_ZRD, DO_W, VMCV, LGKV) do {                \
    if (DO_ZRD) { _Pragma("unroll") for (int n = 0; n < 4; ++n)                     \
        ZL[n] = *(const short8*)((bb) + (NXT) * 4096 + zoff[n]); }                  \
    if (DO_W) { WLOAD(WL[0], wpc0); WLOAD(WL[1], wpc1);                             \
                WLOAD(WL[2], wpc2); WLOAD(WL[3], wpc3); }                           \
    asm volatile("s_waitcnt vmcnt(" #VMCV ") lgkmcnt(" #LGKV ")" ::: "memory");     \
    __builtin_amdgcn_sched_barrier(0);                                              \
    __builtin_amdgcn_s_setprio(1);                                                  \
    _Pragma("unroll") for (int n = 0; n < 4; ++n) {                                 \
        acc[0][n] = MFMA(WU[0], ZU[n], acc[0][n]);                                  \
        acc[1][n] = MFMA(WU[1], ZU[n], acc[1][n]);                                  \
        acc[2][n] = MFMA(WU[2], ZU[n], acc[2][n]);                                  \
        acc[3][n] = MFMA(WU[3], ZU[n], acc[3][n]);                                  \
    }                                                                               \
    __builtin_amdgcn_s_setprio(0);                                                  \
    __builtin_amdgcn_sched_barrier(0);                                              \
} while (0)

    // Prologue: W(0,0) -> wA, stage(0); drain; publish.
    WLOAD(wA[0], wpc0); WLOAD(wA[1], wpc1); WLOAD(wA[2], wpc2); WLOAD(wA[3], wpc3);
    STAGE_SS(0);
    asm volatile("s_waitcnt vmcnt(0)\n\ts_barrier" ::: "memory");

    for (int S = 0; S < 11; ++S) {
        const char* bb = (const char*)lds + (S & 1) * 16384;
#pragma unroll
        for (int n = 0; n < 4; ++n) zA[n] = *(const short8*)(bb + zoff[n]);
        STAGE_SS(S + 1);
        KSUB(bb, 1, zA, zB, wA, wB, 1, 1, 8, 4);   // ks0
        KSUB(bb, 2, zB, zA, wB, wA, 1, 1, 4, 4);   // ks1 (forces stage(S+1))
        KSUB(bb, 3, zA, zB, wA, wB, 1, 1, 4, 4);   // ks2
        KSUB(bb, 0, zB, zA, wB, wA, 0, 1, 4, 0);   // ks3 (loads W(S+1,0))
        asm volatile("s_barrier" ::: "memory");
    }
    {   // S = 11: no stage, W chains end at W(11,3)
        const char* bb = (const char*)lds + (11 & 1) * 16384;
#pragma unroll
        for (int n = 0; n < 4; ++n) zA[n] = *(const short8*)(bb + zoff[n]);
        KSUB(bb, 1, zA, zB, wA, wB, 1, 1, 4, 4);   // ks0
        KSUB(bb, 2, zB, zA, wB, wA, 1, 1, 4, 4);   // ks1
        KSUB(bb, 3, zA, zB, wA, wB, 1, 1, 4, 4);   // ks2
        KSUB(bb, 0, zB, zA, wB, wA, 0, 0, 0, 0);   // ks3
    }

#undef KSUB
#undef WLOAD
#undef STAGE_SS
#undef GLLDS
#undef MFMA

    // ---- epilogue: D row = f = lq*4+reg, col = l = lr (verified r1-r7)
#pragma unroll
    for (int ns = 0; ns < 4; ++ns) {
        const int m = Mbase + ns * 16 + lr;
        const int b = m >> lsh;
        const int l = m & (Lv - 1);
        float* orow = ob + ((size_t)b * F_ << lsh) + l;
#pragma unroll
        for (int ms = 0; ms < 4; ++ms) {
            const int f0 = ftBase + wid * 64 + ms * 16 + lq * 4;
            const f32x4 v = acc[ms][ns];
#pragma unroll
            for (int r = 0; r < 4; ++r)
                orow[(size_t)(f0 + r) << lsh] = v[r] + __ldg(&bias[f0 + r]);
        }
    }
}

extern "C" void kernel_launch(void* const* d_in, const int* in_sizes, int n_in,
                              void* d_out, int out_size, void* d_ws, size_t ws_size,
                              hipStream_t stream)
{
    const float* q    = (const float*)d_in[0];
    const float* a    = (const float*)d_in[1];
    const float* W    = (const float*)d_in[2];
    const float* bias = (const float*)d_in[3];
    float* out = (float*)d_out;

    unsigned short* xq  = (unsigned short*)d_ws;
    unsigned short* xa  = xq + XQ_ELEMS;
    unsigned short* wfr = xa + XA_ELEMS;
    // ws needed: (XQ+XA+WF)*2 = 52.6 MB

    prep_x<<<(XROWS * 76 + 255) / 256, 256, 0, stream>>>(q, a, xq, xa);
    prep_w2<<<WF_ELEMS / 256, 256, 0, stream>>>(W, wfr);
    qa_gemm<<<2560, 256, 0, stream>>>(xq, xa, wfr, bias, out);
}

// Round 9
// 162.369 us; speedup vs baseline: 1.0835x; 1.0106x over previous
//
#include <hip/hip_runtime.h>

// Shapes
#define NB   256      // batch
#define E0   300      // embedding
#define EP   304      // padded embedding
#define F_   512      // features
#define KP   1536     // padded K (5*304=1520 -> 48*32)
#define NKT  48       // K-steps of 32
#define LQ_  64
#define LA_  256

typedef __attribute__((ext_vector_type(4))) float f32x4;
typedef __attribute__((ext_vector_type(8))) short short8;

#define XQ_ELEMS (NB * (LQ_ + 4) * EP)   // 5,292,032
#define XA_ELEMS (NB * (LA_ + 4) * EP)   // 20,234,240
#define WF_ELEMS (F_ * KP)               // 786,432 (fragment-packed)
#define OUTQ_ELEMS ((size_t)NB * F_ * LQ_)
#define XROWS (NB * (LQ_ + 4) + NB * (LA_ + 4))   // 83,968

__device__ __forceinline__ unsigned short f2bf(float x) {
    unsigned int u = __float_as_uint(x);
    u = u + 0x7fffu + ((u >> 16) & 1u);   // RNE
    return (unsigned short)(u >> 16);
}

// Zero-padded bf16 x with halo, flat-indexed dense blocks.
__global__ void prep_x(const float* __restrict__ q, const float* __restrict__ a,
                       unsigned short* __restrict__ xq, unsigned short* __restrict__ xa)
{
    int idx = blockIdx.x * 256 + threadIdx.x;
    if (idx >= XROWS * 76) return;
    int row = idx / 76;
    int col = idx - row * 76;

    const float* src;
    unsigned short* dst;
    bool valid;
    if (row < NB * (LQ_ + 4)) {
        int b = row / (LQ_ + 4), lp = row - b * (LQ_ + 4);
        dst = xq + (size_t)row * EP;
        valid = (lp >= 2 && lp < 2 + LQ_);
        src = q + ((size_t)b * LQ_ + (lp - 2)) * E0;
    } else {
        int r2 = row - NB * (LQ_ + 4);
        int b = r2 / (LA_ + 4), lp = r2 - b * (LA_ + 4);
        dst = xa + (size_t)r2 * EP;
        valid = (lp >= 2 && lp < 2 + LA_);
        src = a + ((size_t)b * LA_ + (lp - 2)) * E0;
    }
    unsigned long long pk = 0ull;
    if (valid && col < 75) {   // rows are 1200B stride -> float4-aligned
        const float4 v = reinterpret_cast<const float4*>(src)[col];
        pk = (unsigned long long)f2bf(v.x)
           | ((unsigned long long)f2bf(v.y) << 16)
           | ((unsigned long long)f2bf(v.z) << 32)
           | ((unsigned long long)f2bf(v.w) << 48);
    }
    *reinterpret_cast<unsigned long long*>(dst + (size_t)col * 4) = pk;
}

// Fragment-packed W: chunk (tile16, kc) is 1024B holding the exact per-lane
// A-operand of mfma_16x16x32: lane holds f = tile16*16 + (lane&15),
// k' = kc*32 + (lane>>4)*8 + j.  (Verified r1-r8.)
__global__ void prep_w2(const float* __restrict__ W, unsigned short* __restrict__ wfr)
{
    int idx = blockIdx.x * 256 + threadIdx.x;     // grid = 32*48*512 shorts
    int j    = idx & 7;
    int lane = (idx >> 3) & 63;
    int chunk = idx >> 9;
    int kc = chunk % NKT;
    int tile16 = chunk / NKT;
    int f  = tile16 * 16 + (lane & 15);
    int kp = kc * 32 + (lane >> 4) * 8 + j;
    int jj = kp / EP;
    int e  = kp - jj * EP;
    float v = (kp < 5 * EP && e < E0) ? W[(size_t)(jj * E0 + e) * F_ + f] : 0.f;
    wfr[idx] = f2bf(v);
}

// 256f x 64l tile, 4 waves (wave = 64f x 64l, acc[4][4]), BK=128 super-steps.
// r9: deeper prefetch on both operand streams, one barrier per super-step.
//   Z: ring-3 LDS (3 x 16 KB); stage(S+2) issued at ks2 of S -> full-ss window.
//   W: L2->reg, 2 ksubs deep, 3 register groups w0/w1/w2 (group k%3, rotation
//      period 3 -> ss loop unrolled by 3).
// Per-wave in-order VMEM ledger (4 W-loads = one WLD4; 4 DMA = one stage):
//   ss S issue: ks0 WLD4->W(4S+2); ks1 WLD4->W(4S+3); ks2 WLD4->W(4S+4) then
//   stage(S+2); ks3 WLD4->W(4S+5).
//   Steady fences (need W(4S+ks) retired): ks0 after-W = [st(S+1),W+1,W+2] = 12
//   -> vmcnt(12); ks1 = [W+2,W+3] = 8 (forces st(S+1), issued 1 full ss ago);
//   ks2 = [W+3,W+4,st(S+2)] = 12; ks3 = [W+4,st(S+2),W+5] = 12.  lgkm 4/4/4/0.
//   S=10 (no stage): 12/8/8/8.  S=11 (W loads only ks0,ks1): 8/8/4/0.
//   Publication: st(S+1) retired at ks1 fence of S, before end-of-S barrier;
//   buf (S+1)%3 is read only after that barrier.  Ring-3 WAR: stage(S+2) hits
//   buf read in S-1; those ds_reads drained at S-1's ks3 lgkm(0) before the
//   end-of-(S-1) barrier, after which the stage is issued.
__global__ __launch_bounds__(256, 3) void qa_gemm(
    const unsigned short* __restrict__ xq,
    const unsigned short* __restrict__ xa,
    const unsigned short* __restrict__ wfr,
    const float* __restrict__ bias,
    float* __restrict__ out)
{
    __shared__ __align__(16) unsigned short lds[3 * 8192];   // 48 KB Z-ring

    const int bid = blockIdx.x;
    const int wg  = (bid & 7) * 320 + (bid >> 3);   // XCD swizzle, 2560 % 8 == 0

    const unsigned short* xp;
    float* ob;
    int Mbase, lsh, Lp, ftBase;
    if (wg < 512) {                 // question: 256 l-tiles x 2 f-halves
        Mbase  = (wg >> 1) * 64;
        ftBase = (wg & 1) * 256;
        xp = xq; lsh = 6; Lp = LQ_ + 4;
        ob = out;
    } else {                        // answer: 1024 l-tiles x 2 f-halves
        const int id = wg - 512;
        Mbase  = (id >> 1) * 64;
        ftBase = (id & 1) * 256;
        xp = xa; lsh = 8; Lp = LA_ + 4;
        ob = out + OUTQ_ELEMS;
    }
    const int Lv = 1 << lsh;

    const int tid  = threadIdx.x;
    const int lane = tid & 63;
    const int wid  = tid >> 6;      // wave = f-slice (0..3); all share the l-tile
    const int lq   = lane >> 4;
    const int lr   = lane & 15;

    // ---- Z staging geometry (swizzle verified r1-r8): wave stages 16 rows/ksub
    const int s_c  = (lane & 3) ^ ((lane >> 3) & 3);
    const int sub  = lane >> 2;
    const int mr0 = Mbase + wid * 16 + sub;
    const unsigned short* gZ0 = xp + (size_t)((mr0 >> lsh) * Lp + (mr0 & (Lv - 1))) * EP + s_c * 8;
    const int dz0 = wid * 512;      // shorts, within each 2048-short ksub block

#define GLLDS(p, d) __builtin_amdgcn_global_load_lds(                               \
        (const __attribute__((address_space(1))) void*)(p),                         \
        (__attribute__((address_space(3))) void*)(d), 16, 0, 0)
// Stage super-tile T into ring buf RB3 (=T%3, passed literal) as 4 ksub blocks
#define STAGE_SS(T, RB3) do { const int rb = (RB3) * 8192; const size_t ko = (size_t)(T) * 128; \
    GLLDS(gZ0 + ko +  0, lds + rb + 0 * 2048 + dz0);                                \
    GLLDS(gZ0 + ko + 32, lds + rb + 1 * 2048 + dz0);                                \
    GLLDS(gZ0 + ko + 64, lds + rb + 2 * 2048 + dz0);                                \
    GLLDS(gZ0 + ko + 96, lds + rb + 3 * 2048 + dz0); } while (0)

    // ---- W fragment pointers (frag = 512 shorts; each WLOAD advances one kc)
    const unsigned short* wpc0 = wfr + (size_t)((ftBase >> 4) + wid * 4 + 0) * NKT * 512 + lane * 8;
    const unsigned short* wpc1 = wfr + (size_t)((ftBase >> 4) + wid * 4 + 1) * NKT * 512 + lane * 8;
    const unsigned short* wpc2 = wfr + (size_t)((ftBase >> 4) + wid * 4 + 2) * NKT * 512 + lane * 8;
    const unsigned short* wpc3 = wfr + (size_t)((ftBase >> 4) + wid * 4 + 3) * NKT * 512 + lane * 8;

#define WLOAD(dst, p) do {                                                           \
    asm volatile("global_load_dwordx4 %0, %1, off" : "=v"(dst) : "v"(p) : "memory"); \
    (p) += 512; } while (0)
#define WLD4(G) do { WLOAD(G[0], wpc0); WLOAD(G[1], wpc1);                           \
                     WLOAD(G[2], wpc2); WLOAD(G[3], wpc3); } while (0)

    // ---- Z fragment LDS offsets within a ksub block (bytes), verified r1-r8
    const int cs = (lq ^ ((lr >> 1) & 3)) * 16;
    int zoff[4];
#pragma unroll
    for (int n = 0; n < 4; ++n) zoff[n] = (n * 16 + lr) * 64 + cs;

    f32x4 acc[4][4] = {};
    short8 w0[4], w1[4], w2[4];

#define MFMA(a, b, c) __builtin_amdgcn_mfma_f32_16x16x32_bf16((a), (b), (c), 0, 0, 0)

#define FENCE(VM, LG) do {                                                           \
    asm volatile("s_waitcnt vmcnt(" #VM ") lgkmcnt(" #LG ")" ::: "memory");          \
    __builtin_amdgcn_sched_barrier(0); } while (0)

#define MFMA16(WU, ZU) do {                                                          \
    __builtin_amdgcn_s_setprio(1);                                                   \
    _Pragma("unroll") for (int n = 0; n < 4; ++n) {                                  \
        acc[0][n] = MFMA(WU[0], ZU[n], acc[0][n]);                                   \
        acc[1][n] = MFMA(WU[1], ZU[n], acc[1][n]);                                   \
        acc[2][n] = MFMA(WU[2], ZU[n], acc[2][n]);                                   \
        acc[3][n] = MFMA(WU[3], ZU[n], acc[3][n]);                                   \
    }                                                                                \
    __builtin_amdgcn_s_setprio(0);                                                   \
    __builtin_amdgcn_sched_barrier(0); } while (0)

#define ZRD(DST, BLK) do { _Pragma("unroll") for (int n = 0; n < 4; ++n)             \
    DST[n] = *(const short8*)(bb + (BLK) * 4096 + zoff[n]); } while (0)

    // One super-step, phase P (=S%3): WA_=w[P], WB_=w[(P+1)%3], WC_=w[(P+2)%3].
    // Uses: ks0 WA_, ks1 WB_, ks2 WC_, ks3 WA_.  Loads: ks0->WC_, ks1->WA_,
    // ks2->WB_, ks3->WC_ (2 ksubs ahead of use).
#define SSBODY(P, WA_, WB_, WC_, DO_ST, STT, STB, DW2, DW3, V0, V1, V2, V3)          \
{   const char* bb = (const char*)lds + (P) * 16384;                                 \
    short8 zA[4], zB[4];                                                             \
    ZRD(zA, 0);                                                                      \
    /* ks0 */ ZRD(zB, 1); WLD4(WC_);                  FENCE(V0, 4); MFMA16(WA_, zA); \
    /* ks1 */ ZRD(zA, 2); WLD4(WA_);                  FENCE(V1, 4); MFMA16(WB_, zB); \
    /* ks2 */ ZRD(zB, 3); if (DW2) { WLD4(WB_); }                                    \
              if (DO_ST) { STAGE_SS(STT, STB); }      FENCE(V2, 4); MFMA16(WC_, zA); \
    /* ks3 */ if (DW3) { WLD4(WC_); }                 FENCE(V3, 0); MFMA16(WA_, zB); \
    asm volatile("s_barrier" ::: "memory");                                          \
}

    // Prologue: W(0)->w0, W(1)->w1, stage(0)->buf0, stage(1)->buf1; drain; publish.
    WLD4(w0); WLD4(w1);
    STAGE_SS(0, 0); STAGE_SS(1, 1);
    asm volatile("s_waitcnt vmcnt(0)\n\ts_barrier" ::: "memory");

    for (int Sb = 0; Sb < 9; Sb += 3) {     // S = 0..8 (steady, with stage)
        SSBODY(0, w0, w1, w2, 1, Sb + 2, 2, 1, 1, 12, 8, 12, 12);
        SSBODY(1, w1, w2, w0, 1, Sb + 3, 0, 1, 1, 12, 8, 12, 12);
        SSBODY(2, w2, w0, w1, 1, Sb + 4, 1, 1, 1, 12, 8, 12, 12);
    }
    // S = 9: steady, stages tile 11 -> buf 2
    SSBODY(0, w0, w1, w2, 1, 11, 2, 1, 1, 12, 8, 12, 12);
    // S = 10: no stage
    SSBODY(1, w1, w2, w0, 0, 0, 0, 1, 1, 12, 8, 8, 8);
    // S = 11: no stage, W loads only at ks0 (W46) and ks1 (W47)
    SSBODY(2, w2, w0, w1, 0, 0, 0, 0, 0, 8, 8, 4, 0);

#undef SSBODY
#undef ZRD
#undef MFMA16
#undef FENCE
#undef WLD4
#undef WLOAD
#undef STAGE_SS
#undef GLLDS
#undef MFMA

    // ---- epilogue: D row = f = lq*4+reg, col = l = lr (verified r1-r8)
#pragma unroll
    for (int ns = 0; ns < 4; ++ns) {
        const int m = Mbase + ns * 16 + lr;
        const int b = m >> lsh;
        const int l = m & (Lv - 1);
        float* orow = ob + ((size_t)b * F_ << lsh) + l;
#pragma unroll
        for (int ms = 0; ms < 4; ++ms) {
            const int f0 = ftBase + wid * 64 + ms * 16 + lq * 4;
            const f32x4 v = acc[ms][ns];
#pragma unroll
            for (int r = 0; r < 4; ++r)
                orow[(size_t)(f0 + r) << lsh] = v[r] + __ldg(&bias[f0 + r]);
        }
    }
}

extern "C" void kernel_launch(void* const* d_in, const int* in_sizes, int n_in,
                              void* d_out, int out_size, void* d_ws, size_t ws_size,
                              hipStream_t stream)
{
    const float* q    = (const float*)d_in[0];
    const float* a    = (const float*)d_in[1];
    const float* W    = (const float*)d_in[2];
    const float* bias = (const float*)d_in[3];
    float* out = (float*)d_out;

    unsigned short* xq  = (unsigned short*)d_ws;
    unsigned short* xa  = xq + XQ_ELEMS;
    unsigned short* wfr = xa + XA_ELEMS;
    // ws needed: (XQ+XA+WF)*2 = 52.6 MB

    prep_x<<<(XROWS * 76 + 255) / 256, 256, 0, stream>>>(q, a, xq, xa);
    prep_w2<<<WF_ELEMS / 256, 256, 0, stream>>>(W, wfr);
    qa_gemm<<<2560, 256, 0, stream>>>(xq, xa, wfr, bias, out);
}